// Round 1
// baseline (9968.912 us; speedup 1.0000x reference)
//
#include <hip/hip_runtime.h>
#include <hip/hip_fp16.h>

#define PLANE 262144   // 512*512
#define NC 21
#define NB 8
#define NPIX (NB*PLANE)

__device__ __forceinline__ float2 h2f(unsigned int u) {
  union { unsigned int u; __half2 h; } x; x.u = u;
  return __half22float2(x.h);
}
__device__ __forceinline__ unsigned int f2h(float a, float b) {
  union { unsigned int u; __half2 h; } x;
  x.h = __floats2half2_rn(a, b);
  return x.u;
}

// ---------------- prep: edge = exp(-|sobel(gray)|) ----------------
__global__ __launch_bounds__(256)
void k_edge(const float* __restrict__ img, __half* __restrict__ edge16) {
  int id = blockIdx.x*256 + threadIdx.x;
  int b = id >> 18;
  int rem = id & (PLANE-1);
  int y = rem >> 9, x = rem & 511;
  const float* ib = img + (size_t)b*3*PLANE;
  float g[3][3];
#pragma unroll
  for (int dy=0; dy<3; ++dy)
#pragma unroll
    for (int dx=0; dx<3; ++dx) {
      int yy = y+dy-1, xx = x+dx-1;
      float v = 0.f;
      if (yy>=0 && yy<512 && xx>=0 && xx<512) {
        int o = (yy<<9)|xx;
        v = 0.299f*ib[o] + 0.587f*ib[o+PLANE] + 0.114f*ib[o+2*PLANE];
      }
      g[dy][dx]=v;
    }
  float gxv = (g[0][2]-g[0][0]) + 2.f*(g[1][2]-g[1][0]) + (g[2][2]-g[2][0]);
  float gyv = (g[2][0]-g[0][0]) + 2.f*(g[2][1]-g[0][1]) + (g[2][2]-g[0][2]);
  float mag = sqrtf(gxv*gxv + gyv*gyv + 1e-6f);
  edge16[id] = __float2half(__expf(-mag));
}

// ---------------- prep: rnorm = 1/(avgpool3(edge)+1e-6) ----------------
__global__ __launch_bounds__(256)
void k_rnorm(const __half* __restrict__ edge16, float* __restrict__ rnorm) {
  int id = blockIdx.x*256 + threadIdx.x;
  int b = id >> 18;
  int rem = id & (PLANE-1);
  int y = rem >> 9, x = rem & 511;
  const __half* eb = edge16 + (size_t)b*PLANE;
  float s = 0.f;
#pragma unroll
  for (int dy=-1; dy<=1; ++dy)
#pragma unroll
    for (int dx=-1; dx<=1; ++dx) {
      int yy = y+dy, xx = x+dx;
      if (yy>=0 && yy<512 && xx>=0 && xx<512) s += __half2float(eb[(yy<<9)|xx]);
    }
  rnorm[id] = 1.f/(s*(1.f/9.f) + 1e-6f);
}

// ---------------- prep: compat == identity? ----------------
__global__ void k_flag(const float* __restrict__ compat, int* __restrict__ flag) {
  __shared__ int ok;
  if (threadIdx.x==0) ok = 1;
  __syncthreads();
  int bad = 0;
  for (int i = threadIdx.x; i < NC*NC; i += 256) {
    float exp = ((i/NC) == (i%NC)) ? 1.f : 0.f;
    if (compat[i] != exp) bad = 1;
  }
  if (bad) atomicAnd(&ok, 0);
  __syncthreads();
  if (threadIdx.x==0) flag[0] = ok;
}

// ---------------- prep: unary fp32 -> fp16 ----------------
__global__ __launch_bounds__(256)
void k_cvt(const float* __restrict__ u, __half* __restrict__ u16) {
  size_t q = (size_t)blockIdx.x*256 + threadIdx.x;
  float4 v = reinterpret_cast<const float4*>(u)[q];
  uint2 w; w.x = f2h(v.x, v.y); w.y = f2h(v.z, v.w);
  reinterpret_cast<uint2*>(u16)[q] = w;
}

// ---------------- Q0 = softmax(unary) -> fp16 ----------------
__global__ __launch_bounds__(256)
void k_softmax0(const float* __restrict__ unary, __half* __restrict__ Y) {
  int q = blockIdx.x*256 + threadIdx.x;           // quad id, [0, NPIX/4)
  int b = q >> 16;
  int rem = q & 65535;
  size_t base = (size_t)b*NC*(PLANE>>2) + rem;
  const float4* up = reinterpret_cast<const float4*>(unary);
  float v[NC][4];
  float mx0=-3e38f,mx1=-3e38f,mx2=-3e38f,mx3=-3e38f;
#pragma unroll
  for (int c=0;c<NC;++c) {
    float4 t = up[base + (size_t)c*(PLANE>>2)];
    v[c][0]=t.x; v[c][1]=t.y; v[c][2]=t.z; v[c][3]=t.w;
    mx0=fmaxf(mx0,t.x); mx1=fmaxf(mx1,t.y); mx2=fmaxf(mx2,t.z); mx3=fmaxf(mx3,t.w);
  }
  float s0=0,s1=0,s2=0,s3=0;
#pragma unroll
  for (int c=0;c<NC;++c) {
    float e0=__expf(v[c][0]-mx0), e1=__expf(v[c][1]-mx1);
    float e2=__expf(v[c][2]-mx2), e3=__expf(v[c][3]-mx3);
    v[c][0]=e0; v[c][1]=e1; v[c][2]=e2; v[c][3]=e3;
    s0+=e0; s1+=e1; s2+=e2; s3+=e3;
  }
  float r0=1.f/s0, r1=1.f/s1, r2=1.f/s2, r3=1.f/s3;
  uint2* yp = reinterpret_cast<uint2*>(Y);
#pragma unroll
  for (int c=0;c<NC;++c) {
    uint2 w; w.x=f2h(v[c][0]*r0, v[c][1]*r1); w.y=f2h(v[c][2]*r2, v[c][3]*r3);
    yp[base + (size_t)c*(PLANE>>2)] = w;
  }
}

// ---------------- fused CRF iteration ----------------
// tile 64x16 px, 256 threads, thread = 4-wide quad; messages for all 21
// channels held in registers; 5x5 & 3x3 pools via column sums + sliding
// horizontal windows from fp16 LDS tiles.

#define LOAD_U(c, u0,u1,u2,u3) \
  float u0,u1,u2,u3; \
  if (U16) { uint2 w_ = reinterpret_cast<const uint2*>(uptr)[qbase + (size_t)(c)*cq]; \
    float2 t0_=h2f(w_.x), t1_=h2f(w_.y); u0=t0_.x; u1=t0_.y; u2=t1_.x; u3=t1_.y; } \
  else { float4 v_ = reinterpret_cast<const float4*>(uptr)[qbase + (size_t)(c)*cq]; \
    u0=v_.x; u1=v_.y; u2=v_.z; u3=v_.w; }

#define ACCUM_COMPAT(c, a0,a1,a2,a3) \
  float a0=0.f,a1=0.f,a2=0.f,a3=0.f; \
  _Pragma("unroll") \
  for (int d=0; d<NC; ++d) { float cf_ = compat[(c)*NC+d]; \
    a0 += cf_*msgr[d][0]; a1 += cf_*msgr[d][1]; a2 += cf_*msgr[d][2]; a3 += cf_*msgr[d][3]; }

template<bool U16, bool OUTF32>
__global__ __launch_bounds__(256, 2)
void k_iter(const __half* __restrict__ Qin,
            void* __restrict__ Qout,
            const void* __restrict__ uptr,
            const __half* __restrict__ edge16,
            const float* __restrict__ rnorm,
            const float* __restrict__ swp,
            const float* __restrict__ bwp,
            const float* __restrict__ compat,
            const int* __restrict__ flag)
{
  __shared__ __half qt[20][72];
  __shared__ __half et[20][72];

  const int tid = threadIdx.x;
  const int tx = tid & 15;
  const int ty = tid >> 4;
  const int x0 = blockIdx.x << 6;
  const int y0 = blockIdx.y << 4;
  const int b  = blockIdx.z;
  const __half HZERO = __float2half(0.f);

  // staging decomposition: 20 rows x 68 cols = 1360 halves, <=6 slots/thread
  int sdst[6], ssrc[6];
#pragma unroll
  for (int j=0;j<6;++j) {
    int idx = tid + j*256;
    if (idx < 1360) {
      int r = idx / 68;
      int i = idx - r*68;
      int sy = y0 - 2 + r;
      int sx = x0 - 2 + i;
      sdst[j] = r*72 + i;
      ssrc[j] = (sy>=0 && sy<512 && sx>=0 && sx<512) ? ((sy<<9)|sx) : -1;
    } else { sdst[j] = -1; ssrc[j] = -1; }
  }

  { // edge tile once per block
    const __half* ep = edge16 + (size_t)b*PLANE;
    __half* etf = &et[0][0];
#pragma unroll
    for (int j=0;j<6;++j) if (sdst[j]>=0) etf[sdst[j]] = (ssrc[j]>=0) ? ep[ssrc[j]] : HZERO;
  }

  const float sw  = fmaxf(swp[0], 0.f);
  const float bw  = fmaxf(bwp[0], 0.f);
  const float csw = sw * 0.04f;          // sw/25
  const float b9  = bw * (1.f/9.f);      // bw/9

  const int gy  = y0 + ty;
  const int gx  = x0 + (tx<<2);
  const int pix = (gy<<9) | gx;

  const float4 rn = *reinterpret_cast<const float4*>(rnorm + (size_t)b*PLANE + pix);
  const float cb0 = b9*rn.x, cb1 = b9*rn.y, cb2 = b9*rn.z, cb3 = b9*rn.w;

  float msgr[NC][4];
  const __half* qb  = Qin + (size_t)b*NC*PLANE;
  __half* qtf = &qt[0][0];

#pragma unroll
  for (int c=0;c<NC;++c) {
    __syncthreads();   // protect qt from previous channel's readers
    const __half* qp = qb + (size_t)c*PLANE;
#pragma unroll
    for (int j=0;j<6;++j) if (sdst[j]>=0) qtf[sdst[j]] = (ssrc[j]>=0) ? qp[ssrc[j]] : HZERO;
    __syncthreads();

    float cs8[8] = {0,0,0,0,0,0,0,0};
    float ce8[8] = {0,0,0,0,0,0,0,0};
#pragma unroll
    for (int dy=0;dy<5;++dy) {
      const uint2 qa = *reinterpret_cast<const uint2*>(&qt[ty+dy][tx<<2]);
      const uint2 qc = *reinterpret_cast<const uint2*>(&qt[ty+dy][(tx<<2)+4]);
      float f[8];
      { float2 t=h2f(qa.x); f[0]=t.x; f[1]=t.y;
        t=h2f(qa.y); f[2]=t.x; f[3]=t.y;
        t=h2f(qc.x); f[4]=t.x; f[5]=t.y;
        t=h2f(qc.y); f[6]=t.x; f[7]=t.y; }
#pragma unroll
      for (int i=0;i<8;++i) cs8[i] += f[i];
      if (dy>=1 && dy<=3) {
        const uint2 ea = *reinterpret_cast<const uint2*>(&et[ty+dy][tx<<2]);
        const uint2 ec = *reinterpret_cast<const uint2*>(&et[ty+dy][(tx<<2)+4]);
        float e[8];
        { float2 t=h2f(ea.x); e[0]=t.x; e[1]=t.y;
          t=h2f(ea.y); e[2]=t.x; e[3]=t.y;
          t=h2f(ec.x); e[4]=t.x; e[5]=t.y;
          t=h2f(ec.y); e[6]=t.x; e[7]=t.y; }
#pragma unroll
        for (int i=1;i<7;++i) ce8[i] += f[i]*e[i];
      }
    }
    float v0 = cs8[0]+cs8[1]+cs8[2]+cs8[3]+cs8[4];
    float v1 = v0 - cs8[0] + cs8[5];
    float v2 = v1 - cs8[1] + cs8[6];
    float v3 = v2 - cs8[2] + cs8[7];
    float w0 = ce8[1]+ce8[2]+ce8[3];
    float w1 = w0 - ce8[1] + ce8[4];
    float w2 = w1 - ce8[2] + ce8[5];
    float w3 = w2 - ce8[3] + ce8[6];
    msgr[c][0] = csw*v0 + cb0*w0;
    msgr[c][1] = csw*v1 + cb1*w1;
    msgr[c][2] = csw*v2 + cb2*w2;
    msgr[c][3] = csw*v3 + cb3*w3;
  }

  // ---- phase 2: (optional compat) + softmax over channels, in registers ----
  const int fl = flag[0];
  const size_t qbase = (((size_t)b*NC*PLANE) >> 2) + (size_t)(pix >> 2);
  const size_t cq = PLANE >> 2;
  float mx0=-3e38f, mx1=-3e38f, mx2=-3e38f, mx3=-3e38f;

  if (fl) {   // identity compat fast path
#pragma unroll
    for (int c=0;c<NC;++c) {
      LOAD_U(c, u0,u1,u2,u3)
      msgr[c][0] = u0 - msgr[c][0];
      msgr[c][1] = u1 - msgr[c][1];
      msgr[c][2] = u2 - msgr[c][2];
      msgr[c][3] = u3 - msgr[c][3];
      mx0=fmaxf(mx0,msgr[c][0]); mx1=fmaxf(mx1,msgr[c][1]);
      mx2=fmaxf(mx2,msgr[c][2]); mx3=fmaxf(mx3,msgr[c][3]);
    }
    float s0=0,s1=0,s2=0,s3=0;
#pragma unroll
    for (int c=0;c<NC;++c) {
      float e0=__expf(msgr[c][0]-mx0), e1=__expf(msgr[c][1]-mx1);
      float e2=__expf(msgr[c][2]-mx2), e3=__expf(msgr[c][3]-mx3);
      msgr[c][0]=e0; msgr[c][1]=e1; msgr[c][2]=e2; msgr[c][3]=e3;
      s0+=e0; s1+=e1; s2+=e2; s3+=e3;
    }
    float r0=1.f/s0, r1=1.f/s1, r2=1.f/s2, r3=1.f/s3;
#pragma unroll
    for (int c=0;c<NC;++c) {
      float o0=msgr[c][0]*r0, o1=msgr[c][1]*r1, o2=msgr[c][2]*r2, o3=msgr[c][3]*r3;
      if (OUTF32) {
        reinterpret_cast<float4*>(Qout)[qbase + (size_t)c*cq] = make_float4(o0,o1,o2,o3);
      } else {
        uint2 w; w.x=f2h(o0,o1); w.y=f2h(o2,o3);
        reinterpret_cast<uint2*>(Qout)[qbase + (size_t)c*cq] = w;
      }
    }
  } else {    // general compat: recompute logits per pass (register-light)
#pragma unroll 1
    for (int c=0;c<NC;++c) {
      ACCUM_COMPAT(c, a0,a1,a2,a3)
      LOAD_U(c, u0,u1,u2,u3)
      mx0=fmaxf(mx0,u0-a0); mx1=fmaxf(mx1,u1-a1);
      mx2=fmaxf(mx2,u2-a2); mx3=fmaxf(mx3,u3-a3);
    }
    float s0=0,s1=0,s2=0,s3=0;
#pragma unroll 1
    for (int c=0;c<NC;++c) {
      ACCUM_COMPAT(c, a0,a1,a2,a3)
      LOAD_U(c, u0,u1,u2,u3)
      s0+=__expf(u0-a0-mx0); s1+=__expf(u1-a1-mx1);
      s2+=__expf(u2-a2-mx2); s3+=__expf(u3-a3-mx3);
    }
    float r0=1.f/s0, r1=1.f/s1, r2=1.f/s2, r3=1.f/s3;
#pragma unroll 1
    for (int c=0;c<NC;++c) {
      ACCUM_COMPAT(c, a0,a1,a2,a3)
      LOAD_U(c, u0,u1,u2,u3)
      float o0=__expf(u0-a0-mx0)*r0, o1=__expf(u1-a1-mx1)*r1;
      float o2=__expf(u2-a2-mx2)*r2, o3=__expf(u3-a3-mx3)*r3;
      if (OUTF32) {
        reinterpret_cast<float4*>(Qout)[qbase + (size_t)c*cq] = make_float4(o0,o1,o2,o3);
      } else {
        uint2 w; w.x=f2h(o0,o1); w.y=f2h(o2,o3);
        reinterpret_cast<uint2*>(Qout)[qbase + (size_t)c*cq] = w;
      }
    }
  }
}

extern "C" void kernel_launch(void* const* d_in, const int* in_sizes, int n_in,
                              void* d_out, int out_size, void* d_ws, size_t ws_size,
                              hipStream_t stream)
{
  const float* unary  = (const float*)d_in[0];
  const float* image  = (const float*)d_in[1];
  const float* compat = (const float*)d_in[2];
  const float* swp    = (const float*)d_in[3];
  const float* bwp    = (const float*)d_in[4];

  // ws layout (bytes): X fp16 Q buffer | edge16 | rnorm | flag | (opt) u16
  char* ws = (char*)d_ws;
  __half* X      = (__half*)(ws + 0);            // 88,080,384 B
  __half* edge16 = (__half*)(ws + 88080384);     //  4,194,304 B
  float*  rnorm  = (float*) (ws + 92274688);     //  8,388,608 B
  int*    flag   = (int*)   (ws + 100663296);    //        256 B
  __half* u16    = (__half*)(ws + 100663552);    // 88,080,384 B (optional)
  if (ws_size < (size_t)100663552) return;       // cannot run without scratch
  const bool use_u16 = (ws_size >= (size_t)188743936);

  __half* Y  = (__half*)d_out;   // d_out doubles as fp16 scratch during iters
  float* out = (float*)d_out;

  k_edge   <<<dim3(8192), dim3(256), 0, stream>>>(image, edge16);
  k_rnorm  <<<dim3(8192), dim3(256), 0, stream>>>(edge16, rnorm);
  k_flag   <<<dim3(1),    dim3(256), 0, stream>>>(compat, flag);
  if (use_u16) k_cvt<<<dim3(43008), dim3(256), 0, stream>>>(unary, u16);
  k_softmax0<<<dim3(2048), dim3(256), 0, stream>>>(unary, Y);

  const void* up = use_u16 ? (const void*)u16 : (const void*)unary;
  dim3 gi(8, 32, NB), bi(256);
  // Q0 -> Y(d_out,fp16); odd iters Y->X; even iters X->Y; iter10 X -> d_out fp32
  for (int it = 1; it <= 10; ++it) {
    const __half* qin = (it & 1) ? Y : X;
    if (it == 10) {
      if (use_u16) k_iter<true , true ><<<gi,bi,0,stream>>>(qin,(void*)out,up,edge16,rnorm,swp,bwp,compat,flag);
      else         k_iter<false, true ><<<gi,bi,0,stream>>>(qin,(void*)out,up,edge16,rnorm,swp,bwp,compat,flag);
    } else {
      void* qout = (it & 1) ? (void*)X : (void*)Y;
      if (use_u16) k_iter<true , false><<<gi,bi,0,stream>>>(qin,qout,up,edge16,rnorm,swp,bwp,compat,flag);
      else         k_iter<false, false><<<gi,bi,0,stream>>>(qin,qout,up,edge16,rnorm,swp,bwp,compat,flag);
    }
  }
}

// Round 2
// 6256.490 us; speedup vs baseline: 1.5934x; 1.5934x over previous
//
#include <hip/hip_runtime.h>
#include <hip/hip_fp16.h>

#define PLANE 262144   // 512*512
#define NC 21
#define NB 8
#define NPIX (NB*PLANE)

__device__ __forceinline__ float2 h2f(unsigned int u) {
  union { unsigned int u; __half2 h; } x; x.u = u;
  return __half22float2(x.h);
}
__device__ __forceinline__ unsigned int f2h(float a, float b) {
  union { unsigned int u; __half2 h; } x;
  x.h = __floats2half2_rn(a, b);
  return x.u;
}

// ---------------- prep: edge = exp(-|sobel(gray)|) ----------------
__global__ __launch_bounds__(256)
void k_edge(const float* __restrict__ img, __half* __restrict__ edge16) {
  int id = blockIdx.x*256 + threadIdx.x;
  int b = id >> 18;
  int rem = id & (PLANE-1);
  int y = rem >> 9, x = rem & 511;
  const float* ib = img + (size_t)b*3*PLANE;
  float g[3][3];
#pragma unroll
  for (int dy=0; dy<3; ++dy)
#pragma unroll
    for (int dx=0; dx<3; ++dx) {
      int yy = y+dy-1, xx = x+dx-1;
      float v = 0.f;
      if (yy>=0 && yy<512 && xx>=0 && xx<512) {
        int o = (yy<<9)|xx;
        v = 0.299f*ib[o] + 0.587f*ib[o+PLANE] + 0.114f*ib[o+2*PLANE];
      }
      g[dy][dx]=v;
    }
  float gxv = (g[0][2]-g[0][0]) + 2.f*(g[1][2]-g[1][0]) + (g[2][2]-g[2][0]);
  float gyv = (g[2][0]-g[0][0]) + 2.f*(g[2][1]-g[0][1]) + (g[2][2]-g[0][2]);
  float mag = sqrtf(gxv*gxv + gyv*gyv + 1e-6f);
  edge16[id] = __float2half(__expf(-mag));
}

// ---------------- prep: rnorm = 1/(avgpool3(edge)+1e-6) ----------------
__global__ __launch_bounds__(256)
void k_rnorm(const __half* __restrict__ edge16, float* __restrict__ rnorm) {
  int id = blockIdx.x*256 + threadIdx.x;
  int b = id >> 18;
  int rem = id & (PLANE-1);
  int y = rem >> 9, x = rem & 511;
  const __half* eb = edge16 + (size_t)b*PLANE;
  float s = 0.f;
#pragma unroll
  for (int dy=-1; dy<=1; ++dy)
#pragma unroll
    for (int dx=-1; dx<=1; ++dx) {
      int yy = y+dy, xx = x+dx;
      if (yy>=0 && yy<512 && xx>=0 && xx<512) s += __half2float(eb[(yy<<9)|xx]);
    }
  rnorm[id] = 1.f/(s*(1.f/9.f) + 1e-6f);
}

// ---------------- prep: compat == identity? ----------------
__global__ void k_flag(const float* __restrict__ compat, int* __restrict__ flag) {
  __shared__ int ok;
  if (threadIdx.x==0) ok = 1;
  __syncthreads();
  int bad = 0;
  for (int i = threadIdx.x; i < NC*NC; i += 256) {
    float exp = ((i/NC) == (i%NC)) ? 1.f : 0.f;
    if (compat[i] != exp) bad = 1;
  }
  if (bad) atomicAnd(&ok, 0);
  __syncthreads();
  if (threadIdx.x==0) flag[0] = ok;
}

// ---------------- prep: unary fp32 -> fp16 ----------------
__global__ __launch_bounds__(256)
void k_cvt(const float* __restrict__ u, __half* __restrict__ u16) {
  size_t q = (size_t)blockIdx.x*256 + threadIdx.x;
  float4 v = reinterpret_cast<const float4*>(u)[q];
  uint2 w; w.x = f2h(v.x, v.y); w.y = f2h(v.z, v.w);
  reinterpret_cast<uint2*>(u16)[q] = w;
}

// ---------------- Q0 = softmax(unary) -> fp16 ----------------
__global__ __launch_bounds__(256)
void k_softmax0(const float* __restrict__ unary, __half* __restrict__ Y) {
  int q = blockIdx.x*256 + threadIdx.x;           // quad id, [0, NPIX/4)
  int b = q >> 16;
  int rem = q & 65535;
  size_t base = (size_t)b*NC*(PLANE>>2) + rem;
  const float4* up = reinterpret_cast<const float4*>(unary);
  float v[NC][4];
  float mx0=-3e38f,mx1=-3e38f,mx2=-3e38f,mx3=-3e38f;
#pragma unroll
  for (int c=0;c<NC;++c) {
    float4 t = up[base + (size_t)c*(PLANE>>2)];
    v[c][0]=t.x; v[c][1]=t.y; v[c][2]=t.z; v[c][3]=t.w;
    mx0=fmaxf(mx0,t.x); mx1=fmaxf(mx1,t.y); mx2=fmaxf(mx2,t.z); mx3=fmaxf(mx3,t.w);
  }
  float s0=0,s1=0,s2=0,s3=0;
#pragma unroll
  for (int c=0;c<NC;++c) {
    float e0=__expf(v[c][0]-mx0), e1=__expf(v[c][1]-mx1);
    float e2=__expf(v[c][2]-mx2), e3=__expf(v[c][3]-mx3);
    v[c][0]=e0; v[c][1]=e1; v[c][2]=e2; v[c][3]=e3;
    s0+=e0; s1+=e1; s2+=e2; s3+=e3;
  }
  float r0=1.f/s0, r1=1.f/s1, r2=1.f/s2, r3=1.f/s3;
  uint2* yp = reinterpret_cast<uint2*>(Y);
#pragma unroll
  for (int c=0;c<NC;++c) {
    uint2 w; w.x=f2h(v[c][0]*r0, v[c][1]*r1); w.y=f2h(v[c][2]*r2, v[c][3]*r3);
    yp[base + (size_t)c*(PLANE>>2)] = w;
  }
}

// ---------------- fused CRF iteration ----------------
// tile 64x16 px, 256 threads, thread = 4-wide quad; messages for all 21
// channels held in registers; 5x5 & 3x3 pools via column sums + sliding
// horizontal windows from fp16 LDS tiles.
// NOTE: NO min-waves launch bound here. R1 post-mortem: __launch_bounds__(256,2)
// capped VGPRs at 128 < the ~140 live values -> scratch spills -> 2.4 GB/iter
// of HBM spill traffic (WRITE_SIZE 1.55 GB vs 88 MB of real output).

#define LOAD_U(c, u0,u1,u2,u3) \
  float u0,u1,u2,u3; \
  if (U16) { uint2 w_ = reinterpret_cast<const uint2*>(uptr)[qbase + (size_t)(c)*cq]; \
    float2 t0_=h2f(w_.x), t1_=h2f(w_.y); u0=t0_.x; u1=t0_.y; u2=t1_.x; u3=t1_.y; } \
  else { float4 v_ = reinterpret_cast<const float4*>(uptr)[qbase + (size_t)(c)*cq]; \
    u0=v_.x; u1=v_.y; u2=v_.z; u3=v_.w; }

#define ACCUM_COMPAT(c, a0,a1,a2,a3) \
  float a0=0.f,a1=0.f,a2=0.f,a3=0.f; \
  _Pragma("unroll") \
  for (int d=0; d<NC; ++d) { float cf_ = compat[(c)*NC+d]; \
    a0 += cf_*msgr[d][0]; a1 += cf_*msgr[d][1]; a2 += cf_*msgr[d][2]; a3 += cf_*msgr[d][3]; }

template<bool U16, bool OUTF32>
__global__ __launch_bounds__(256)
void k_iter(const __half* __restrict__ Qin,
            void* __restrict__ Qout,
            const void* __restrict__ uptr,
            const __half* __restrict__ edge16,
            const float* __restrict__ rnorm,
            const float* __restrict__ swp,
            const float* __restrict__ bwp,
            const float* __restrict__ compat,
            const int* __restrict__ flag)
{
  __shared__ __half qt[20][72];
  __shared__ __half et[20][72];

  const int tid = threadIdx.x;
  const int tx = tid & 15;
  const int ty = tid >> 4;
  const int x0 = blockIdx.x << 6;
  const int y0 = blockIdx.y << 4;
  const int b  = blockIdx.z;
  const __half HZERO = __float2half(0.f);

  // staging decomposition: 20 rows x 68 cols = 1360 halves, <=6 slots/thread
  int sdst[6], ssrc[6];
#pragma unroll
  for (int j=0;j<6;++j) {
    int idx = tid + j*256;
    if (idx < 1360) {
      int r = idx / 68;
      int i = idx - r*68;
      int sy = y0 - 2 + r;
      int sx = x0 - 2 + i;
      sdst[j] = r*72 + i;
      ssrc[j] = (sy>=0 && sy<512 && sx>=0 && sx<512) ? ((sy<<9)|sx) : -1;
    } else { sdst[j] = -1; ssrc[j] = -1; }
  }

  { // edge tile once per block
    const __half* ep = edge16 + (size_t)b*PLANE;
    __half* etf = &et[0][0];
#pragma unroll
    for (int j=0;j<6;++j) if (sdst[j]>=0) etf[sdst[j]] = (ssrc[j]>=0) ? ep[ssrc[j]] : HZERO;
  }

  const float sw  = fmaxf(swp[0], 0.f);
  const float bw  = fmaxf(bwp[0], 0.f);
  const float csw = sw * 0.04f;          // sw/25
  const float b9  = bw * (1.f/9.f);      // bw/9

  const int gy  = y0 + ty;
  const int gx  = x0 + (tx<<2);
  const int pix = (gy<<9) | gx;

  const float4 rn = *reinterpret_cast<const float4*>(rnorm + (size_t)b*PLANE + pix);
  const float cb0 = b9*rn.x, cb1 = b9*rn.y, cb2 = b9*rn.z, cb3 = b9*rn.w;

  float msgr[NC][4];
  const __half* qb  = Qin + (size_t)b*NC*PLANE;
  __half* qtf = &qt[0][0];

#pragma unroll
  for (int c=0;c<NC;++c) {
    __syncthreads();   // protect qt from previous channel's readers
    const __half* qp = qb + (size_t)c*PLANE;
#pragma unroll
    for (int j=0;j<6;++j) if (sdst[j]>=0) qtf[sdst[j]] = (ssrc[j]>=0) ? qp[ssrc[j]] : HZERO;
    __syncthreads();

    float cs8[8] = {0,0,0,0,0,0,0,0};
    float ce8[8] = {0,0,0,0,0,0,0,0};
#pragma unroll
    for (int dy=0;dy<5;++dy) {
      const uint2 qa = *reinterpret_cast<const uint2*>(&qt[ty+dy][tx<<2]);
      const uint2 qc = *reinterpret_cast<const uint2*>(&qt[ty+dy][(tx<<2)+4]);
      float f[8];
      { float2 t=h2f(qa.x); f[0]=t.x; f[1]=t.y;
        t=h2f(qa.y); f[2]=t.x; f[3]=t.y;
        t=h2f(qc.x); f[4]=t.x; f[5]=t.y;
        t=h2f(qc.y); f[6]=t.x; f[7]=t.y; }
#pragma unroll
      for (int i=0;i<8;++i) cs8[i] += f[i];
      if (dy>=1 && dy<=3) {
        const uint2 ea = *reinterpret_cast<const uint2*>(&et[ty+dy][tx<<2]);
        const uint2 ec = *reinterpret_cast<const uint2*>(&et[ty+dy][(tx<<2)+4]);
        float e[8];
        { float2 t=h2f(ea.x); e[0]=t.x; e[1]=t.y;
          t=h2f(ea.y); e[2]=t.x; e[3]=t.y;
          t=h2f(ec.x); e[4]=t.x; e[5]=t.y;
          t=h2f(ec.y); e[6]=t.x; e[7]=t.y; }
#pragma unroll
        for (int i=1;i<7;++i) ce8[i] += f[i]*e[i];
      }
    }
    float v0 = cs8[0]+cs8[1]+cs8[2]+cs8[3]+cs8[4];
    float v1 = v0 - cs8[0] + cs8[5];
    float v2 = v1 - cs8[1] + cs8[6];
    float v3 = v2 - cs8[2] + cs8[7];
    float w0 = ce8[1]+ce8[2]+ce8[3];
    float w1 = w0 - ce8[1] + ce8[4];
    float w2 = w1 - ce8[2] + ce8[5];
    float w3 = w2 - ce8[3] + ce8[6];
    msgr[c][0] = csw*v0 + cb0*w0;
    msgr[c][1] = csw*v1 + cb1*w1;
    msgr[c][2] = csw*v2 + cb2*w2;
    msgr[c][3] = csw*v3 + cb3*w3;
  }

  // ---- phase 2: (optional compat) + softmax over channels, in registers ----
  const int fl = flag[0];
  const size_t qbase = (((size_t)b*NC*PLANE) >> 2) + (size_t)(pix >> 2);
  const size_t cq = PLANE >> 2;
  float mx0=-3e38f, mx1=-3e38f, mx2=-3e38f, mx3=-3e38f;

  if (fl) {   // identity compat fast path
#pragma unroll
    for (int c=0;c<NC;++c) {
      LOAD_U(c, u0,u1,u2,u3)
      msgr[c][0] = u0 - msgr[c][0];
      msgr[c][1] = u1 - msgr[c][1];
      msgr[c][2] = u2 - msgr[c][2];
      msgr[c][3] = u3 - msgr[c][3];
      mx0=fmaxf(mx0,msgr[c][0]); mx1=fmaxf(mx1,msgr[c][1]);
      mx2=fmaxf(mx2,msgr[c][2]); mx3=fmaxf(mx3,msgr[c][3]);
    }
    float s0=0,s1=0,s2=0,s3=0;
#pragma unroll
    for (int c=0;c<NC;++c) {
      float e0=__expf(msgr[c][0]-mx0), e1=__expf(msgr[c][1]-mx1);
      float e2=__expf(msgr[c][2]-mx2), e3=__expf(msgr[c][3]-mx3);
      msgr[c][0]=e0; msgr[c][1]=e1; msgr[c][2]=e2; msgr[c][3]=e3;
      s0+=e0; s1+=e1; s2+=e2; s3+=e3;
    }
    float r0=1.f/s0, r1=1.f/s1, r2=1.f/s2, r3=1.f/s3;
#pragma unroll
    for (int c=0;c<NC;++c) {
      float o0=msgr[c][0]*r0, o1=msgr[c][1]*r1, o2=msgr[c][2]*r2, o3=msgr[c][3]*r3;
      if (OUTF32) {
        reinterpret_cast<float4*>(Qout)[qbase + (size_t)c*cq] = make_float4(o0,o1,o2,o3);
      } else {
        uint2 w; w.x=f2h(o0,o1); w.y=f2h(o2,o3);
        reinterpret_cast<uint2*>(Qout)[qbase + (size_t)c*cq] = w;
      }
    }
  } else {    // general compat: recompute logits per pass (register-light)
#pragma unroll 1
    for (int c=0;c<NC;++c) {
      ACCUM_COMPAT(c, a0,a1,a2,a3)
      LOAD_U(c, u0,u1,u2,u3)
      mx0=fmaxf(mx0,u0-a0); mx1=fmaxf(mx1,u1-a1);
      mx2=fmaxf(mx2,u2-a2); mx3=fmaxf(mx3,u3-a3);
    }
    float s0=0,s1=0,s2=0,s3=0;
#pragma unroll 1
    for (int c=0;c<NC;++c) {
      ACCUM_COMPAT(c, a0,a1,a2,a3)
      LOAD_U(c, u0,u1,u2,u3)
      s0+=__expf(u0-a0-mx0); s1+=__expf(u1-a1-mx1);
      s2+=__expf(u2-a2-mx2); s3+=__expf(u3-a3-mx3);
    }
    float r0=1.f/s0, r1=1.f/s1, r2=1.f/s2, r3=1.f/s3;
#pragma unroll 1
    for (int c=0;c<NC;++c) {
      ACCUM_COMPAT(c, a0,a1,a2,a3)
      LOAD_U(c, u0,u1,u2,u3)
      float o0=__expf(u0-a0-mx0)*r0, o1=__expf(u1-a1-mx1)*r1;
      float o2=__expf(u2-a2-mx2)*r2, o3=__expf(u3-a3-mx3)*r3;
      if (OUTF32) {
        reinterpret_cast<float4*>(Qout)[qbase + (size_t)c*cq] = make_float4(o0,o1,o2,o3);
      } else {
        uint2 w; w.x=f2h(o0,o1); w.y=f2h(o2,o3);
        reinterpret_cast<uint2*>(Qout)[qbase + (size_t)c*cq] = w;
      }
    }
  }
}

extern "C" void kernel_launch(void* const* d_in, const int* in_sizes, int n_in,
                              void* d_out, int out_size, void* d_ws, size_t ws_size,
                              hipStream_t stream)
{
  const float* unary  = (const float*)d_in[0];
  const float* image  = (const float*)d_in[1];
  const float* compat = (const float*)d_in[2];
  const float* swp    = (const float*)d_in[3];
  const float* bwp    = (const float*)d_in[4];

  // ws layout (bytes): X fp16 Q buffer | edge16 | rnorm | flag | (opt) u16
  char* ws = (char*)d_ws;
  __half* X      = (__half*)(ws + 0);            // 88,080,384 B
  __half* edge16 = (__half*)(ws + 88080384);     //  4,194,304 B
  float*  rnorm  = (float*) (ws + 92274688);     //  8,388,608 B
  int*    flag   = (int*)   (ws + 100663296);    //        256 B
  __half* u16    = (__half*)(ws + 100663552);    // 88,080,384 B (optional)
  if (ws_size < (size_t)100663552) return;       // cannot run without scratch
  const bool use_u16 = (ws_size >= (size_t)188743936);

  __half* Y  = (__half*)d_out;   // d_out doubles as fp16 scratch during iters
  float* out = (float*)d_out;

  k_edge   <<<dim3(8192), dim3(256), 0, stream>>>(image, edge16);
  k_rnorm  <<<dim3(8192), dim3(256), 0, stream>>>(edge16, rnorm);
  k_flag   <<<dim3(1),    dim3(256), 0, stream>>>(compat, flag);
  if (use_u16) k_cvt<<<dim3(43008), dim3(256), 0, stream>>>(unary, u16);
  k_softmax0<<<dim3(2048), dim3(256), 0, stream>>>(unary, Y);

  const void* up = use_u16 ? (const void*)u16 : (const void*)unary;
  dim3 gi(8, 32, NB), bi(256);
  // Q0 -> Y(d_out,fp16); odd iters Y->X; even iters X->Y; iter10 X -> d_out fp32
  for (int it = 1; it <= 10; ++it) {
    const __half* qin = (it & 1) ? Y : X;
    if (it == 10) {
      if (use_u16) k_iter<true , true ><<<gi,bi,0,stream>>>(qin,(void*)out,up,edge16,rnorm,swp,bwp,compat,flag);
      else         k_iter<false, true ><<<gi,bi,0,stream>>>(qin,(void*)out,up,edge16,rnorm,swp,bwp,compat,flag);
    } else {
      void* qout = (it & 1) ? (void*)X : (void*)Y;
      if (use_u16) k_iter<true , false><<<gi,bi,0,stream>>>(qin,qout,up,edge16,rnorm,swp,bwp,compat,flag);
      else         k_iter<false, false><<<gi,bi,0,stream>>>(qin,qout,up,edge16,rnorm,swp,bwp,compat,flag);
    }
  }
}